// Round 6
// baseline (7963.535 us; speedup 1.0000x reference)
//
#include <hip/hip_runtime.h>
#include <math.h>

#define H    512
#define H4   2048
#define OPS  12
#define E    112
#define NWG  128
#define NT   256

// ---- workspace float offsets (ws[0..15] reserved: [0] barrier counter) ----
#define WS_EW    16                     // 12*2048: emb @ Wih0^T (per action)
#define WS_GUM   (WS_EW + 12*H4)        // 1344 gumbel noise
#define WS_B0    (WS_GUM + E*OPS)       // bih0+bhh0 (4H)
#define WS_B1    (WS_B0 + H4)           // bih1+bhh1 (4H)
#define WS_G0    (WS_B1 + H4)           // cell-0 gates (4H), incl. B0+EW
#define WS_G1B   (WS_G0 + H4)           // Whh1 @ h1 (4H)
#define WS_G1    (WS_G1B + H4)          // cell-1 summed gates (4H)
#define WS_HM    (WS_G1 + H4)           // controller hidden (H)
#define WS_ST    (WS_HM + H)            // (fallback path) 2 bufs x [h0,h1,c0,c1] x H

__device__ __forceinline__ float sigf(float x) { return 1.f / (1.f + expf(-x)); }

// JAX threefry2x32, key = PRNGKey(42) = (0,42), 20 rounds
__device__ __forceinline__ void threefry_42(unsigned x0, unsigned x1,
                                            unsigned& o0, unsigned& o1) {
  const unsigned k0 = 0u, k1 = 42u;
  const unsigned k2 = k0 ^ k1 ^ 0x1BD11BDAu;
  x0 += k0; x1 += k1;
#define TF_R(rot) { x0 += x1; x1 = (x1 << rot) | (x1 >> (32 - rot)); x1 ^= x0; }
  TF_R(13) TF_R(15) TF_R(26) TF_R(6)
  x0 += k1; x1 += k2 + 1u;
  TF_R(17) TF_R(29) TF_R(16) TF_R(24)
  x0 += k2; x1 += k0 + 2u;
  TF_R(13) TF_R(15) TF_R(26) TF_R(6)
  x0 += k0; x1 += k1 + 3u;
  TF_R(17) TF_R(29) TF_R(16) TF_R(24)
  x0 += k1; x1 += k2 + 4u;
  TF_R(13) TF_R(15) TF_R(26) TF_R(6)
  x0 += k2; x1 += k0 + 5u;
#undef TF_R
  o0 = x0; o1 = x1;
}

// JAX partitionable threefry 32-bit draw: bits = y0 ^ y1 of counts (0, t)
__device__ __forceinline__ float bits_to_gumbel(unsigned bits) {
  unsigned fb = (bits >> 9) | 0x3f800000u;
  float u = __uint_as_float(fb) - 1.0f;
  u = u + 1.17549435e-38f;
  u = fmaxf(1.17549435e-38f, u);
  return -logf(-logf(u));
}

__device__ __forceinline__ float decode_temp(const void* temp_p) {
  float tf = *(const float*)temp_p;
  float a = fabsf(tf);
  if (a > 1e-6f && a < 1e6f) return tf;
  int ti = *(const int*)temp_p;
  if (ti != 0 && ti > -1000000 && ti < 1000000) return (float)ti;
  double td = *(const double*)temp_p;
  double ad = fabs(td);
  if (ad > 1e-6 && ad < 1e6) return (float)td;
  return 1.0f;
}

// grid barrier: monotonic counter, release/acquire fences both sides
__device__ __forceinline__ void gbar(unsigned* ctr, unsigned& barno) {
  __syncthreads();
  __threadfence();
  if (threadIdx.x == 0) {
    barno += 1;
    __hip_atomic_fetch_add(ctr, 1u, __ATOMIC_RELEASE, __HIP_MEMORY_SCOPE_AGENT);
    unsigned tgt = barno * NWG;
    while (__hip_atomic_load(ctr, __ATOMIC_ACQUIRE, __HIP_MEMORY_SCOPE_AGENT) < tgt)
      __builtin_amdgcn_s_sleep(1);
  }
  __syncthreads();
  __threadfence();
}

// ---------------------------------------------------------------------------
__global__ void k_init(float* out, unsigned* ctr) {
  int t = blockIdx.x * blockDim.x + threadIdx.x;
  if (t < 3 * E) out[t] = -7777.0f;
  if (t == 0) *ctr = 0u;
}

__global__ void k_diag(float* out, float v) {
  if (threadIdx.x == 0 && blockIdx.x == 0) out[0] = v;
}

// ======================= PERSISTENT KERNEL =================================
__global__ void __launch_bounds__(NT)
policy_persist(const void* temp_p,
               const float* __restrict__ h0_in, const float* __restrict__ c0_in,
               const float* __restrict__ Wih0,  const float* __restrict__ Whh0,
               const float* __restrict__ bih0,  const float* __restrict__ bhh0,
               const float* __restrict__ Wih1,  const float* __restrict__ Whh1,
               const float* __restrict__ bih1,  const float* __restrict__ bhh1,
               const float* __restrict__ emb,   const float* __restrict__ cW1,
               const float* __restrict__ cb1,   const float* __restrict__ cW2,
               const float* __restrict__ cb2,
               float* __restrict__ out, float* ws, unsigned* ctr) {
  __shared__ __align__(16) float sh0[H], sh1[H], sc0s[H], sc1s[H];
  __shared__ float spart[4][4];
  __shared__ int s_act;

  const int tid = threadIdx.x;
  const int bid = blockIdx.x;
  const int gt  = bid * NT + tid;
  unsigned barno = 0;

  const float invt = 1.f / decode_temp(temp_p);
  float* EW  = ws + WS_EW;
  float* GUM = ws + WS_GUM;
  float* B0c = ws + WS_B0;
  float* B1c = ws + WS_B1;
  float* G0v = ws + WS_G0;
  float* G1B = ws + WS_G1B;
  float* G1v = ws + WS_G1;
  float* HM  = ws + WS_HM;

  // state into per-WG LDS (identical in every WG, updated redundantly)
  for (int j = tid; j < H; j += NT) {
    sh0[j]  = h0_in[j];
    sh1[j]  = h0_in[H + j];
    sc0s[j] = c0_in[j];
    sc1s[j] = c0_in[H + j];
  }

  // -------- setup: EW, gumbel, fused biases (verified round-5 logic) -------
  {
    const int N_EW  = 12 * H4;
    const int N_GUM = N_EW + E * OPS;
    const int N_B0  = N_GUM + H4;
    const int N_B1  = N_B0 + H4;
    if (gt < N_EW) {
      int a = gt >> 11, r = gt & (H4 - 1);
      const float* er = emb + a * H;
      const float* wr = Wih0 + (size_t)r * H;
      float acc = 0.f;
      for (int k = 0; k < H; k += 4) {
        float4 e4 = *(const float4*)(er + k);
        float4 w4 = *(const float4*)(wr + k);
        acc += e4.x * w4.x + e4.y * w4.y + e4.z * w4.z + e4.w * w4.w;
      }
      EW[gt] = acc;
    } else if (gt < N_GUM) {
      int p = gt - N_EW;
      unsigned y0, y1;
      threefry_42(0u, (unsigned)p, y0, y1);
      GUM[p] = bits_to_gumbel(y0 ^ y1);
    } else if (gt < N_B0) {
      int j = gt - N_GUM;
      B0c[j] = bih0[j] + bhh0[j];
    } else if (gt < N_B1) {
      int j = gt - N_B0;
      B1c[j] = bih1[j] + bhh1[j];
    }
  }
  gbar(ctr, barno);

  int aprev = -1;

#pragma unroll 1
  for (int i = 0; i < E; ++i) {
    // ---- A: G0 = Whh0@h0 + B0 (+EW[aprev]), G1B = Whh1@h1 (8 lanes/row) ---
    {
      int row = gt >> 3, seg = gt & 7;
      const float* wr = (row < H4 ? Whh0 + (size_t)row * H
                                  : Whh1 + (size_t)(row - H4) * H) + seg * 64;
      const float* hv = (row < H4 ? sh0 : sh1) + seg * 64;
      float acc = 0.f;
#pragma unroll
      for (int k = 0; k < 64; k += 4) {
        float4 w4 = *(const float4*)(wr + k);
        float4 h4 = *(const float4*)(hv + k);
        acc += w4.x * h4.x + w4.y * h4.y + w4.z * h4.z + w4.w * h4.w;
      }
      acc += __shfl_xor(acc, 1);
      acc += __shfl_xor(acc, 2);
      acc += __shfl_xor(acc, 4);
      if (seg == 0) {
        if (row < H4) {
          float g = acc + B0c[row];
          if (aprev >= 0) g += EW[aprev * H4 + row];
          G0v[row] = g;
        } else {
          G1B[row - H4] = acc;
        }
      }
    }
    gbar(ctr, barno);

    // ---- PW0 (redundant per WG): cell-0 pointwise -> sh0, sc0s ------------
#pragma unroll
    for (int e = 0; e < 2; ++e) {
      int j = tid + e * NT;
      float gi = G0v[j];
      float gf = G0v[H + j];
      float gg = G0v[2 * H + j];
      float go = G0v[3 * H + j];
      float cn = sigf(gf) * sc0s[j] + sigf(gi) * tanhf(gg);
      sc0s[j] = cn;
      sh0[j] = sigf(go) * tanhf(cn);
    }
    __syncthreads();

    // ---- B: G1 = Wih1@h0n + G1B + B1 (16 lanes/row) -----------------------
    {
      int row = gt >> 4, seg = gt & 15;
      const float* wr = Wih1 + (size_t)row * H + seg * 32;
      const float* hv = sh0 + seg * 32;
      float acc = 0.f;
#pragma unroll
      for (int k = 0; k < 32; k += 4) {
        float4 w4 = *(const float4*)(wr + k);
        float4 h4 = *(const float4*)(hv + k);
        acc += w4.x * h4.x + w4.y * h4.y + w4.z * h4.z + w4.w * h4.w;
      }
      acc += __shfl_xor(acc, 1);
      acc += __shfl_xor(acc, 2);
      acc += __shfl_xor(acc, 4);
      acc += __shfl_xor(acc, 8);
      if (seg == 0) G1v[row] = acc + G1B[row] + B1c[row];
    }
    gbar(ctr, barno);

    // ---- PW1 (redundant per WG): cell-1 pointwise -> sh1, sc1s ------------
#pragma unroll
    for (int e = 0; e < 2; ++e) {
      int j = tid + e * NT;
      float gi = G1v[j];
      float gf = G1v[H + j];
      float gg = G1v[2 * H + j];
      float go = G1v[3 * H + j];
      float cn = sigf(gf) * sc1s[j] + sigf(gi) * tanhf(gg);
      sc1s[j] = cn;
      sh1[j] = sigf(go) * tanhf(cn);
    }
    __syncthreads();

    // ---- C: HM = relu(h1n @ W1[i] + cb1[i]), 4 cols per WG ----------------
    {
      int wv = tid >> 6, ln = tid & 63;
      int jl = ln & 3, ks = ln >> 2;
      int jout = bid * 4 + jl;
      const float* w1 = cW1 + (size_t)i * H * H;
      int kbase = wv * 128 + ks * 8;
      float acc = 0.f;
#pragma unroll
      for (int t = 0; t < 8; ++t) {
        int k = kbase + t;
        acc += sh1[k] * w1[(size_t)k * H + jout];
      }
      acc += __shfl_xor(acc, 4);
      acc += __shfl_xor(acc, 8);
      acc += __shfl_xor(acc, 16);
      acc += __shfl_xor(acc, 32);
      if (ln < 4) spart[wv][ln] = acc;
    }
    __syncthreads();
    if (tid < 4) {
      float s = spart[0][tid] + spart[1][tid] + spart[2][tid] + spart[3][tid];
      s += cb1[(size_t)i * H + bid * 4 + tid];
      HM[bid * 4 + tid] = fmaxf(s, 0.f);
    }
    gbar(ctr, barno);

    // ---- D: logits + sampling (redundant per WG; bid 0 writes out) --------
    if (tid < 64) {
      float lg[OPS];
#pragma unroll
      for (int o = 0; o < OPS; ++o) lg[o] = 0.f;
#pragma unroll
      for (int jj = 0; jj < 8; ++jj) {
        int j = jj * 64 + tid;
        float hm = HM[j];
        const float* w2r = cW2 + ((size_t)i * H + j) * OPS;
#pragma unroll
        for (int o = 0; o < OPS; ++o) lg[o] += hm * w2r[o];
      }
#pragma unroll
      for (int s = 1; s < 64; s <<= 1) {
#pragma unroll
        for (int o = 0; o < OPS; ++o) lg[o] += __shfl_xor(lg[o], s);
      }
#pragma unroll
      for (int o = 0; o < OPS; ++o) lg[o] = (lg[o] + cb2[i * OPS + o]) * invt;
      float mx = lg[0];
#pragma unroll
      for (int o = 1; o < OPS; ++o) mx = fmaxf(mx, lg[o]);
      float se = 0.f;
#pragma unroll
      for (int o = 0; o < OPS; ++o) se += expf(lg[o] - mx);
      float logZ = mx + logf(se);
      float best = -1e30f; int act = 0;
#pragma unroll
      for (int o = 0; o < OPS; ++o) {
        float v = lg[o] + GUM[i * OPS + o];
        if (v > best) { best = v; act = o; }
      }
      if (tid == 0) {
        s_act = act;
        if (bid == 0) {
          float lp = lg[act] - logZ;
          float ent = 0.f;
          for (int o = 0; o < OPS; ++o) {
            float l2 = lg[o] - logZ;
            ent -= expf(l2) * l2;
          }
          out[i]         = (float)act;
          out[E + i]     = lp;
          out[2 * E + i] = ent;
        }
      }
    }
    __syncthreads();
    aprev = s_act;
  }
}

// ======================= FALLBACK (proven round-5 chain) ===================
__global__ void __launch_bounds__(256)
k_setup(const float* h0_in, const float* c0_in,
        const float* Wih0, const float* bih0, const float* bhh0,
        const float* bih1, const float* bhh1,
        const float* emb, float* ws) {
  int gt = blockIdx.x * blockDim.x + threadIdx.x;
  const int N_EW  = 12 * H4;
  const int N_GUM = N_EW + E * OPS;
  const int N_B0  = N_GUM + H4;
  const int N_B1  = N_B0 + H4;
  const int N_H   = N_B1 + 2 * H;
  const int N_C   = N_H + 2 * H;
  if (gt < N_EW) {
    int a = gt >> 11, r = gt & (H4 - 1);
    const float* er = emb + a * H;
    const float* wr = Wih0 + (size_t)r * H;
    float acc = 0.f;
    for (int k = 0; k < H; k += 4) {
      float4 e4 = *(const float4*)(er + k);
      float4 w4 = *(const float4*)(wr + k);
      acc += e4.x * w4.x + e4.y * w4.y + e4.z * w4.z + e4.w * w4.w;
    }
    ws[WS_EW + gt] = acc;
  } else if (gt < N_GUM) {
    int p = gt - N_EW;
    unsigned y0, y1;
    threefry_42(0u, (unsigned)p, y0, y1);
    ws[WS_GUM + p] = bits_to_gumbel(y0 ^ y1);
  } else if (gt < N_B0) {
    int j = gt - N_GUM;
    ws[WS_B0 + j] = bih0[j] + bhh0[j];
  } else if (gt < N_B1) {
    int j = gt - N_B0;
    ws[WS_B1 + j] = bih1[j] + bhh1[j];
  } else if (gt < N_H) {
    int j = gt - N_B1;
    ws[WS_ST + j] = h0_in[j];
  } else if (gt < N_C) {
    int j = gt - N_H;
    ws[WS_ST + 2 * H + j] = c0_in[j];
  }
}

__device__ __forceinline__ int do_sample(int li, const void* temp_p,
                                         const float* cW2, const float* cb2,
                                         const float* ws, float* out,
                                         int tid, int bid, int* s_act) {
  if (tid < 64) {
    float lg[OPS];
#pragma unroll
    for (int o = 0; o < OPS; ++o) lg[o] = 0.f;
#pragma unroll
    for (int jj = 0; jj < 8; ++jj) {
      int j = jj * 64 + tid;
      float hm = ws[WS_HM + j];
      const float* w2r = cW2 + ((size_t)li * H + j) * OPS;
#pragma unroll
      for (int o = 0; o < OPS; ++o) lg[o] += hm * w2r[o];
    }
#pragma unroll
    for (int s = 1; s < 64; s <<= 1) {
#pragma unroll
      for (int o = 0; o < OPS; ++o) lg[o] += __shfl_xor(lg[o], s);
    }
    float invt = 1.f / decode_temp(temp_p);
#pragma unroll
    for (int o = 0; o < OPS; ++o) lg[o] = (lg[o] + cb2[li * OPS + o]) * invt;
    float mx = lg[0];
#pragma unroll
    for (int o = 1; o < OPS; ++o) mx = fmaxf(mx, lg[o]);
    float se = 0.f;
#pragma unroll
    for (int o = 0; o < OPS; ++o) se += expf(lg[o] - mx);
    float logZ = mx + logf(se);
    float best = -1e30f; int act = 0;
#pragma unroll
    for (int o = 0; o < OPS; ++o) {
      float v = lg[o] + ws[WS_GUM + li * OPS + o];
      if (v > best) { best = v; act = o; }
    }
    if (tid == 0) {
      *s_act = act;
      if (bid == 0) {
        float lp = lg[act] - logZ;
        float ent = 0.f;
        for (int o = 0; o < OPS; ++o) {
          float l2 = lg[o] - logZ;
          ent -= expf(l2) * l2;
        }
        out[li]         = (float)act;
        out[E + li]     = lp;
        out[2 * E + li] = ent;
      }
    }
  }
  __syncthreads();
  return *s_act;
}

__global__ void __launch_bounds__(256)
k1_sample_gates(int i, const void* temp_p,
                const float* Whh0, const float* Whh1,
                const float* cW2, const float* cb2,
                float* out, float* ws) {
  __shared__ int s_act;
  int tid = threadIdx.x, bid = blockIdx.x;
  int gt = bid * 256 + tid;
  int p = i & 1;
  int a_prev = -1;
  if (i > 0) a_prev = do_sample(i - 1, temp_p, cW2, cb2, ws, out, tid, bid, &s_act);
  int row = gt >> 3, seg = gt & 7;
  const float* wr;
  const float* hv;
  if (row < H4) { wr = Whh0 + (size_t)row * H;        hv = ws + WS_ST + p * 4 * H; }
  else          { wr = Whh1 + (size_t)(row - H4) * H; hv = ws + WS_ST + p * 4 * H + H; }
  wr += seg * 64; hv += seg * 64;
  float acc = 0.f;
#pragma unroll
  for (int k = 0; k < 64; k += 4) {
    float4 w4 = *(const float4*)(wr + k);
    float4 h4 = *(const float4*)(hv + k);
    acc += w4.x * h4.x + w4.y * h4.y + w4.z * h4.z + w4.w * h4.w;
  }
  acc += __shfl_xor(acc, 1);
  acc += __shfl_xor(acc, 2);
  acc += __shfl_xor(acc, 4);
  if (seg == 0) {
    if (row < H4) {
      float g = acc + ws[WS_B0 + row];
      if (a_prev >= 0) g += ws[WS_EW + a_prev * H4 + row];
      ws[WS_G0 + row] = g;
    } else {
      ws[WS_G1B + (row - H4)] = acc;
    }
  }
}

__global__ void __launch_bounds__(256)
k2_cell0_g1(int i, const float* Wih1, float* ws) {
  __shared__ __align__(16) float sh0n[H];
  int tid = threadIdx.x, bid = blockIdx.x;
  int gt = bid * 256 + tid;
  int p = i & 1;
  const float* cst = ws + WS_ST + p * 4 * H + 2 * H;
  float* hst_n = ws + WS_ST + (1 - p) * 4 * H;
  float* cst_n = ws + WS_ST + (1 - p) * 4 * H + 2 * H;
#pragma unroll
  for (int e = 0; e < 2; ++e) {
    int j = tid + e * 256;
    float gi = ws[WS_G0 + j];
    float gf = ws[WS_G0 + H + j];
    float gg = ws[WS_G0 + 2 * H + j];
    float go = ws[WS_G0 + 3 * H + j];
    float cn = sigf(gf) * cst[j] + sigf(gi) * tanhf(gg);
    float hn = sigf(go) * tanhf(cn);
    sh0n[j] = hn;
    if (bid == 0) { cst_n[j] = cn; hst_n[j] = hn; }
  }
  __syncthreads();
  int row = gt >> 3, seg = gt & 7;
  const float* wr = Wih1 + (size_t)row * H + seg * 64;
  float acc = 0.f;
#pragma unroll
  for (int k = 0; k < 64; k += 4) {
    float4 w4 = *(const float4*)(wr + k);
    acc += w4.x * sh0n[seg * 64 + k]     + w4.y * sh0n[seg * 64 + k + 1]
         + w4.z * sh0n[seg * 64 + k + 2] + w4.w * sh0n[seg * 64 + k + 3];
  }
  acc += __shfl_xor(acc, 1);
  acc += __shfl_xor(acc, 2);
  acc += __shfl_xor(acc, 4);
  if (seg == 0) ws[WS_G1 + row] = acc + ws[WS_G1B + row] + ws[WS_B1 + row];
}

__global__ void __launch_bounds__(256)
k3_cell1_mlp(int i, const float* cW1, const float* cb1, float* ws) {
  __shared__ __align__(16) float sh1n[H];
  __shared__ float spart[4][4];
  int tid = threadIdx.x, bid = blockIdx.x;
  int p = i & 1;
  const float* cst = ws + WS_ST + p * 4 * H + 3 * H;
  float* hst_n = ws + WS_ST + (1 - p) * 4 * H + H;
  float* cst_n = ws + WS_ST + (1 - p) * 4 * H + 3 * H;
#pragma unroll
  for (int e = 0; e < 2; ++e) {
    int j = tid + e * 256;
    float gi = ws[WS_G1 + j];
    float gf = ws[WS_G1 + H + j];
    float gg = ws[WS_G1 + 2 * H + j];
    float go = ws[WS_G1 + 3 * H + j];
    float cn = sigf(gf) * cst[j] + sigf(gi) * tanhf(gg);
    float hn = sigf(go) * tanhf(cn);
    sh1n[j] = hn;
    if (bid == 0) { cst_n[j] = cn; hst_n[j] = hn; }
  }
  __syncthreads();
  int wv = tid >> 6, ln = tid & 63;
  int jl = ln & 3, ks = ln >> 2;
  int jout = bid * 4 + jl;
  const float* w1 = cW1 + (size_t)i * H * H;
  int kbase = wv * 128 + ks * 8;
  float acc = 0.f;
#pragma unroll
  for (int t = 0; t < 8; ++t) {
    int k = kbase + t;
    acc += sh1n[k] * w1[(size_t)k * H + jout];
  }
  acc += __shfl_xor(acc, 4);
  acc += __shfl_xor(acc, 8);
  acc += __shfl_xor(acc, 16);
  acc += __shfl_xor(acc, 32);
  if (ln < 4) spart[wv][ln] = acc;
  __syncthreads();
  if (tid < 4) {
    float s = spart[0][tid] + spart[1][tid] + spart[2][tid] + spart[3][tid];
    s += cb1[(size_t)i * H + bid * 4 + tid];
    ws[WS_HM + bid * 4 + tid] = fmaxf(s, 0.f);
  }
}

__global__ void __launch_bounds__(256)
kF_final(const void* temp_p, const float* cW2, const float* cb2,
         float* out, float* ws) {
  __shared__ int s_act;
  do_sample(E - 1, temp_p, cW2, cb2, ws, out, threadIdx.x, blockIdx.x, &s_act);
}

// ===========================================================================
extern "C" void kernel_launch(void* const* d_in, const int* in_sizes, int n_in,
                              void* d_out, int out_size, void* d_ws, size_t ws_size,
                              hipStream_t stream) {
  (void)out_size; (void)ws_size;
  float* out = (float*)d_out;
  float* ws  = (float*)d_ws;
  unsigned* ctr = (unsigned*)d_ws;

  (void)hipGetLastError();

  static const long long expect[16] = {
      1, 1024, 1024, 1048576, 1048576, 2048, 2048,
      1048576, 1048576, 2048, 2048, 6144,
      29360128, 57344, 688128, 1344 };
  int bad = -1;
  if (n_in != 16) bad = 99;
  else {
    for (int i = 0; i < 16; ++i)
      if ((long long)in_sizes[i] != expect[i]) { bad = i; break; }
  }

  k_init<<<2, 256, 0, stream>>>(out, ctr);
  if (bad >= 0) {
    k_diag<<<1, 64, 0, stream>>>(out, 80000.0f + (float)bad);
    return;
  }

  const void*  temp_p = d_in[0];
  const float* h0   = (const float*)d_in[1];
  const float* c0   = (const float*)d_in[2];
  const float* Wih0 = (const float*)d_in[3];
  const float* Whh0 = (const float*)d_in[4];
  const float* bih0 = (const float*)d_in[5];
  const float* bhh0 = (const float*)d_in[6];
  const float* Wih1 = (const float*)d_in[7];
  const float* Whh1 = (const float*)d_in[8];
  const float* bih1 = (const float*)d_in[9];
  const float* bhh1 = (const float*)d_in[10];
  const float* emb  = (const float*)d_in[11];
  const float* cW1  = (const float*)d_in[12];
  const float* cb1  = (const float*)d_in[13];
  const float* cW2  = (const float*)d_in[14];
  const float* cb2  = (const float*)d_in[15];

  policy_persist<<<NWG, NT, 0, stream>>>(
      temp_p, h0, c0, Wih0, Whh0, bih0, bhh0,
      Wih1, Whh1, bih1, bhh1, emb, cW1, cb1, cW2, cb2,
      out, ws, ctr);

  hipError_t e = hipGetLastError();
  if (e != hipSuccess) {
    // proven multi-kernel fallback (recomputes everything from inputs)
    k_setup<<<128, 256, 0, stream>>>(h0, c0, Wih0, bih0, bhh0, bih1, bhh1, emb, ws);
    for (int i = 0; i < E; ++i) {
      k1_sample_gates<<<128, 256, 0, stream>>>(i, temp_p, Whh0, Whh1, cW2, cb2, out, ws);
      k2_cell0_g1<<<64, 256, 0, stream>>>(i, Wih1, ws);
      k3_cell1_mlp<<<128, 256, 0, stream>>>(i, cW1, cb1, ws);
    }
    kF_final<<<1, 256, 0, stream>>>(temp_p, cW2, cb2, out, ws);
  }
}

// Round 7
// 1692.571 us; speedup vs baseline: 4.7050x; 4.7050x over previous
//
#include <hip/hip_runtime.h>
#include <math.h>

#define H    512
#define OPS  12
#define E    112
#define NWG  128
#define NT   256

// ws layout (floats). ws[0] = barrier counter (unsigned). 64B-separated.
#define WS_HB   16                    // 2 parities x [h0(512) | h1(512)]
#define WS_HM   (WS_HB + 2048)        // controller hidden (512)

__device__ __forceinline__ float sigf(float x) { return 1.f / (1.f + expf(-x)); }

// JAX threefry2x32, key = PRNGKey(42) = (0,42), 20 rounds
__device__ __forceinline__ void threefry_42(unsigned x0, unsigned x1,
                                            unsigned& o0, unsigned& o1) {
  const unsigned k0 = 0u, k1 = 42u;
  const unsigned k2 = k0 ^ k1 ^ 0x1BD11BDAu;
  x0 += k0; x1 += k1;
#define TF_R(rot) { x0 += x1; x1 = (x1 << rot) | (x1 >> (32 - rot)); x1 ^= x0; }
  TF_R(13) TF_R(15) TF_R(26) TF_R(6)
  x0 += k1; x1 += k2 + 1u;
  TF_R(17) TF_R(29) TF_R(16) TF_R(24)
  x0 += k2; x1 += k0 + 2u;
  TF_R(13) TF_R(15) TF_R(26) TF_R(6)
  x0 += k0; x1 += k1 + 3u;
  TF_R(17) TF_R(29) TF_R(16) TF_R(24)
  x0 += k1; x1 += k2 + 4u;
  TF_R(13) TF_R(15) TF_R(26) TF_R(6)
  x0 += k2; x1 += k0 + 5u;
#undef TF_R
  o0 = x0; o1 = x1;
}

// JAX partitionable threefry 32-bit draw: bits = y0 ^ y1 of counts (0, t)
__device__ __forceinline__ float bits_to_gumbel(unsigned bits) {
  unsigned fb = (bits >> 9) | 0x3f800000u;
  float u = __uint_as_float(fb) - 1.0f;
  u = u + 1.17549435e-38f;
  u = fmaxf(1.17549435e-38f, u);
  return -logf(-logf(u));
}

__device__ __forceinline__ float decode_temp(const void* temp_p) {
  float tf = *(const float*)temp_p;
  float a = fabsf(tf);
  if (a > 1e-6f && a < 1e6f) return tf;
  int ti = *(const int*)temp_p;
  if (ti != 0 && ti > -1000000 && ti < 1000000) return (float)ti;
  double td = *(const double*)temp_p;
  double ad = fabs(td);
  if (ad > 1e-6 && ad < 1e6) return (float)td;
  return 1.0f;
}

// MALL-coherent scalar access (sc0 sc1): bypasses L1/L2, coherent at Infinity
// Cache. NO cache-maintenance ops are ever required for data moved this way.
__device__ __forceinline__ float scld(const float* p) {
  return __hip_atomic_load(p, __ATOMIC_RELAXED, __HIP_MEMORY_SCOPE_SYSTEM);
}
__device__ __forceinline__ void scst(float* p, float v) {
  __hip_atomic_store(p, v, __ATOMIC_RELAXED, __HIP_MEMORY_SCOPE_SYSTEM);
}

// grid barrier WITHOUT L2 invalidation: all cross-WG data is sc0sc1, so only
// store-completion ordering (vmcnt) is needed before the arrival increment.
__device__ __forceinline__ void gbar(unsigned* ctr, unsigned& barno) {
  __syncthreads();                       // compiler drains vmcnt before s_barrier
  if (threadIdx.x == 0) {
    barno += 1;
    asm volatile("s_waitcnt vmcnt(0)" ::: "memory");
    __hip_atomic_fetch_add(ctr, 1u, __ATOMIC_RELAXED, __HIP_MEMORY_SCOPE_SYSTEM);
    unsigned tgt = barno * NWG;
    while (__hip_atomic_load(ctr, __ATOMIC_RELAXED, __HIP_MEMORY_SCOPE_SYSTEM) < tgt)
      __builtin_amdgcn_s_sleep(2);
  }
  __syncthreads();
}

__global__ void k_init(unsigned* ctr) {
  if (threadIdx.x == 0 && blockIdx.x == 0) *ctr = 0u;
}
__global__ void k_diag(float* out, float v) {
  if (threadIdx.x == 0 && blockIdx.x == 0) out[0] = v;
}

// ===========================================================================
__global__ void __launch_bounds__(NT)
policy_persist(const void* temp_p,
               const float* __restrict__ h0_in, const float* __restrict__ c0_in,
               const float* __restrict__ Wih0,  const float* __restrict__ Whh0,
               const float* __restrict__ bih0,  const float* __restrict__ bhh0,
               const float* __restrict__ Wih1,  const float* __restrict__ Whh1,
               const float* __restrict__ bih1,  const float* __restrict__ bhh1,
               const float* __restrict__ emb,   const float* __restrict__ cW1,
               const float* __restrict__ cb1,   const float* __restrict__ cW2,
               const float* __restrict__ cb2,
               float* __restrict__ out, float* ws, unsigned* ctr) {
  __shared__ __align__(16) float shp0[H], shp1[H], hm[H];
  __shared__ float g0loc[16], g1bloc[16], g1loc[16];
  __shared__ float ewloc[12 * 16], b0loc[16], b1loc[16];
  __shared__ float gum[E * OPS];
  __shared__ float c0loc[4], c1loc[4];
  __shared__ float spart[4][4];
  __shared__ int s_act;

  const int tid = threadIdx.x;
  const int bid = blockIdx.x;
  const int j0  = bid * 4;                       // owned h-columns [j0, j0+4)
  const int cb  = (bid & 7) * 16 + (bid >> 3);   // XCD-grouped HM col-block
  unsigned barno = 0;
  const float invt = 1.f / decode_temp(temp_p);

  float* HB = ws + WS_HB;
  float* HM = ws + WS_HM;

  // ---------------- setup: all WG-local (no cross-WG flow except HB init) ---
  for (int p = tid; p < E * OPS; p += NT) {
    unsigned y0, y1;
    threefry_42(0u, (unsigned)p, y0, y1);
    gum[p] = bits_to_gumbel(y0 ^ y1);
  }
  if (tid < 192) {                       // ewloc[a*16 + ridx], own 16 rows
    int a = tid / 16, ridx = tid % 16;
    int g = ridx >> 2, dj = ridx & 3;
    int row = g * H + j0 + dj;
    const float* er = emb + a * H;
    const float* wr = Wih0 + (size_t)row * H;
    float acc = 0.f;
    for (int k = 0; k < H; k += 4) {
      float4 e4 = *(const float4*)(er + k);
      float4 w4 = *(const float4*)(wr + k);
      acc += e4.x * w4.x + e4.y * w4.y + e4.z * w4.z + e4.w * w4.w;
    }
    ewloc[tid] = acc;
  }
  if (tid < 16) {
    int g = tid >> 2, dj = tid & 3;
    int row = g * H + j0 + dj;
    b0loc[tid] = bih0[row] + bhh0[row];
    b1loc[tid] = bih1[row] + bhh1[row];
  }
  if (tid < 4) {
    c0loc[tid] = c0_in[j0 + tid];
    c1loc[tid] = c0_in[H + j0 + tid];
    scst(&HB[1024 + j0 + tid],     h0_in[j0 + tid]);       // parity-1 h0
    scst(&HB[1024 + H + j0 + tid], h0_in[H + j0 + tid]);   // parity-1 h1
  }
  gbar(ctr, barno);

  int aprev = -1;

#pragma unroll 1
  for (int i = 0; i < E; ++i) {
    const int p = i & 1;
    float* hbR = HB + (1 - p) * 1024;    // previous step's state
    float* hbW = HB + p * 1024;          // this step's state

    // ---- phase A: batched sc loads (h_prev x2, HM for sampling) ----------
    {
      int t2 = tid * 2;
      shp0[t2]     = scld(&hbR[t2]);
      shp0[t2 + 1] = scld(&hbR[t2 + 1]);
      shp1[t2]     = scld(&hbR[H + t2]);
      shp1[t2 + 1] = scld(&hbR[H + t2 + 1]);
      if (i > 0) {
        hm[t2]     = scld(&HM[t2]);
        hm[t2 + 1] = scld(&HM[t2 + 1]);
      }
    }
    __syncthreads();

    // ---- sampling of step i-1 (redundant per WG; bit-identical) ----------
    if (i > 0) {
      if (tid < 64) {
        float lg[OPS];
#pragma unroll
        for (int o = 0; o < OPS; ++o) lg[o] = 0.f;
#pragma unroll
        for (int jj = 0; jj < 8; ++jj) {
          int j = jj * 64 + tid;
          float hmv = hm[j];
          const float* w2r = cW2 + ((size_t)(i - 1) * H + j) * OPS;
#pragma unroll
          for (int o = 0; o < OPS; ++o) lg[o] += hmv * w2r[o];
        }
#pragma unroll
        for (int s = 1; s < 64; s <<= 1) {
#pragma unroll
          for (int o = 0; o < OPS; ++o) lg[o] += __shfl_xor(lg[o], s);
        }
#pragma unroll
        for (int o = 0; o < OPS; ++o) lg[o] = (lg[o] + cb2[(i - 1) * OPS + o]) * invt;
        float mx = lg[0];
#pragma unroll
        for (int o = 1; o < OPS; ++o) mx = fmaxf(mx, lg[o]);
        float se = 0.f;
#pragma unroll
        for (int o = 0; o < OPS; ++o) se += expf(lg[o] - mx);
        float logZ = mx + logf(se);
        float best = -1e30f; int act = 0;
#pragma unroll
        for (int o = 0; o < OPS; ++o) {
          float v = lg[o] + gum[(i - 1) * OPS + o];
          if (v > best) { best = v; act = o; }
        }
        if (tid == 0) {
          s_act = act;
          if (bid == 0) {
            float lp = lg[act] - logZ;
            float ent = 0.f;
            for (int o = 0; o < OPS; ++o) {
              float l2 = lg[o] - logZ;
              ent -= expf(l2) * l2;
            }
            out[i - 1]         = (float)act;
            out[E + i - 1]     = lp;
            out[2 * E + i - 1] = ent;
          }
        }
      }
      __syncthreads();
      aprev = s_act;
    }

    // ---- G0 (cell0, own 16 rows) + G1B (cell1, own 16 rows); 8 lanes/row --
    {
      int rowidx = tid >> 3, lane = tid & 7;   // rowidx 0..31
      int cell = rowidx >> 4;
      int ridx = rowidx & 15;
      int g = ridx >> 2, dj = ridx & 3;
      int row = g * H + j0 + dj;
      const float* wr = (cell ? Whh1 : Whh0) + (size_t)row * H + lane * 64;
      const float* hv = (cell ? shp1 : shp0) + lane * 64;
      float acc = 0.f;
#pragma unroll
      for (int k = 0; k < 64; k += 4) {
        float4 w4 = *(const float4*)(wr + k);
        acc += w4.x * hv[k] + w4.y * hv[k + 1] + w4.z * hv[k + 2] + w4.w * hv[k + 3];
      }
      acc += __shfl_xor(acc, 1);
      acc += __shfl_xor(acc, 2);
      acc += __shfl_xor(acc, 4);
      if (lane == 0) {
        if (cell == 0) {
          float gg = acc + b0loc[ridx];
          if (aprev >= 0) gg += ewloc[aprev * 16 + ridx];
          g0loc[ridx] = gg;
        } else {
          g1bloc[ridx] = acc;
        }
      }
    }
    __syncthreads();

    // ---- PW0 (own 4 columns) -> h0n (sc store), c0 local ------------------
    if (tid < 4) {
      float gi = g0loc[tid];
      float gf = g0loc[4 + tid];
      float gg = g0loc[8 + tid];
      float go = g0loc[12 + tid];
      float cn = sigf(gf) * c0loc[tid] + sigf(gi) * tanhf(gg);
      c0loc[tid] = cn;
      scst(&hbW[j0 + tid], sigf(go) * tanhf(cn));
    }
    gbar(ctr, barno);                    // sync 1

    // ---- phase B: G1 = Wih1@h0n + G1B + B1 (own 16 rows, 16 lanes/row) ---
    {
      int t2 = tid * 2;
      shp0[t2]     = scld(&hbW[t2]);
      shp0[t2 + 1] = scld(&hbW[t2 + 1]);
    }
    __syncthreads();
    {
      int ridx = tid >> 4, lane = tid & 15;
      int g = ridx >> 2, dj = ridx & 3;
      int row = g * H + j0 + dj;
      const float* wr = Wih1 + (size_t)row * H + lane * 32;
      const float* hv = shp0 + lane * 32;
      float acc = 0.f;
#pragma unroll
      for (int k = 0; k < 32; k += 4) {
        float4 w4 = *(const float4*)(wr + k);
        acc += w4.x * hv[k] + w4.y * hv[k + 1] + w4.z * hv[k + 2] + w4.w * hv[k + 3];
      }
      acc += __shfl_xor(acc, 1);
      acc += __shfl_xor(acc, 2);
      acc += __shfl_xor(acc, 4);
      acc += __shfl_xor(acc, 8);
      if (lane == 0) g1loc[ridx] = acc + g1bloc[ridx] + b1loc[ridx];
    }
    __syncthreads();

    // ---- PW1 (own 4 columns) -> h1n (sc store), c1 local ------------------
    if (tid < 4) {
      float gi = g1loc[tid];
      float gf = g1loc[4 + tid];
      float gg = g1loc[8 + tid];
      float go = g1loc[12 + tid];
      float cn = sigf(gf) * c1loc[tid] + sigf(gi) * tanhf(gg);
      c1loc[tid] = cn;
      scst(&hbW[H + j0 + tid], sigf(go) * tanhf(cn));
    }
    gbar(ctr, barno);                    // sync 2

    // ---- phase C: HM cols [cb*4, cb*4+4) = relu(h1n @ W1[i] + b1) --------
    {
      int t2 = tid * 2;
      shp1[t2]     = scld(&hbW[H + t2]);
      shp1[t2 + 1] = scld(&hbW[H + t2 + 1]);
    }
    __syncthreads();
    {
      int wv = tid >> 6, ln = tid & 63;
      int jl = ln & 3, ks = ln >> 2;
      int jout = cb * 4 + jl;
      const float* w1 = cW1 + (size_t)i * H * H;
      int kbase = wv * 128 + ks * 8;
      float acc = 0.f;
#pragma unroll
      for (int t = 0; t < 8; ++t) {
        int k = kbase + t;
        acc += shp1[k] * w1[(size_t)k * H + jout];
      }
      acc += __shfl_xor(acc, 4);
      acc += __shfl_xor(acc, 8);
      acc += __shfl_xor(acc, 16);
      acc += __shfl_xor(acc, 32);
      if (ln < 4) spart[wv][ln] = acc;
    }
    __syncthreads();
    if (tid < 4) {
      float s = spart[0][tid] + spart[1][tid] + spart[2][tid] + spart[3][tid];
      s += cb1[(size_t)i * H + cb * 4 + tid];
      scst(&HM[cb * 4 + tid], fmaxf(s, 0.f));
    }
    gbar(ctr, barno);                    // sync 3
  }

  // ---- final sampling (step E-1), WG 0 writes outputs ---------------------
  {
    int t2 = tid * 2;
    hm[t2]     = scld(&HM[t2]);
    hm[t2 + 1] = scld(&HM[t2 + 1]);
  }
  __syncthreads();
  if (bid == 0 && tid < 64) {
    float lg[OPS];
#pragma unroll
    for (int o = 0; o < OPS; ++o) lg[o] = 0.f;
#pragma unroll
    for (int jj = 0; jj < 8; ++jj) {
      int j = jj * 64 + tid;
      float hmv = hm[j];
      const float* w2r = cW2 + ((size_t)(E - 1) * H + j) * OPS;
#pragma unroll
      for (int o = 0; o < OPS; ++o) lg[o] += hmv * w2r[o];
    }
#pragma unroll
    for (int s = 1; s < 64; s <<= 1) {
#pragma unroll
      for (int o = 0; o < OPS; ++o) lg[o] += __shfl_xor(lg[o], s);
    }
#pragma unroll
    for (int o = 0; o < OPS; ++o) lg[o] = (lg[o] + cb2[(E - 1) * OPS + o]) * invt;
    float mx = lg[0];
#pragma unroll
    for (int o = 1; o < OPS; ++o) mx = fmaxf(mx, lg[o]);
    float se = 0.f;
#pragma unroll
    for (int o = 0; o < OPS; ++o) se += expf(lg[o] - mx);
    float logZ = mx + logf(se);
    float best = -1e30f; int act = 0;
#pragma unroll
    for (int o = 0; o < OPS; ++o) {
      float v = lg[o] + gum[(E - 1) * OPS + o];
      if (v > best) { best = v; act = o; }
    }
    if (tid == 0) {
      float lp = lg[act] - logZ;
      float ent = 0.f;
      for (int o = 0; o < OPS; ++o) {
        float l2 = lg[o] - logZ;
        ent -= expf(l2) * l2;
      }
      out[E - 1]     = (float)act;
      out[2 * E - 1] = lp;
      out[3 * E - 1] = ent;
    }
  }
}

// ===========================================================================
extern "C" void kernel_launch(void* const* d_in, const int* in_sizes, int n_in,
                              void* d_out, int out_size, void* d_ws, size_t ws_size,
                              hipStream_t stream) {
  (void)out_size; (void)ws_size;
  float* out = (float*)d_out;
  float* ws  = (float*)d_ws;
  unsigned* ctr = (unsigned*)d_ws;

  (void)hipGetLastError();

  static const long long expect[16] = {
      1, 1024, 1024, 1048576, 1048576, 2048, 2048,
      1048576, 1048576, 2048, 2048, 6144,
      29360128, 57344, 688128, 1344 };
  int bad = -1;
  if (n_in != 16) bad = 99;
  else {
    for (int i = 0; i < 16; ++i)
      if ((long long)in_sizes[i] != expect[i]) { bad = i; break; }
  }

  k_init<<<1, 64, 0, stream>>>(ctr);
  if (bad >= 0) {
    k_diag<<<1, 64, 0, stream>>>(out, 80000.0f + (float)bad);
    return;
  }

  policy_persist<<<NWG, NT, 0, stream>>>(
      d_in[0],
      (const float*)d_in[1],  (const float*)d_in[2],
      (const float*)d_in[3],  (const float*)d_in[4],
      (const float*)d_in[5],  (const float*)d_in[6],
      (const float*)d_in[7],  (const float*)d_in[8],
      (const float*)d_in[9],  (const float*)d_in[10],
      (const float*)d_in[11], (const float*)d_in[12],
      (const float*)d_in[13], (const float*)d_in[14],
      (const float*)d_in[15],
      out, ws, ctr);

  hipError_t e = hipGetLastError();
  if (e != hipSuccess) {
    k_diag<<<1, 64, 0, stream>>>(out, 90000.0f + (float)(int)e);
  }
}

// Round 8
// 1510.046 us; speedup vs baseline: 5.2737x; 1.1209x over previous
//
#include <hip/hip_runtime.h>
#include <math.h>

#define H    512
#define OPS  12
#define E    112
#define NWG  128
#define NT   256

// ws float offsets. ws[0] = barrier counter.
#define WS_HB   16                    // h0n(512) | h1n(512)
#define WS_HM   (WS_HB + 1024)       // controller hidden (512)

__device__ __forceinline__ float sigf(float x) { return 1.f / (1.f + expf(-x)); }

// JAX threefry2x32, key = PRNGKey(42) = (0,42), 20 rounds
__device__ __forceinline__ void threefry_42(unsigned x0, unsigned x1,
                                            unsigned& o0, unsigned& o1) {
  const unsigned k0 = 0u, k1 = 42u;
  const unsigned k2 = k0 ^ k1 ^ 0x1BD11BDAu;
  x0 += k0; x1 += k1;
#define TF_R(rot) { x0 += x1; x1 = (x1 << rot) | (x1 >> (32 - rot)); x1 ^= x0; }
  TF_R(13) TF_R(15) TF_R(26) TF_R(6)
  x0 += k1; x1 += k2 + 1u;
  TF_R(17) TF_R(29) TF_R(16) TF_R(24)
  x0 += k2; x1 += k0 + 2u;
  TF_R(13) TF_R(15) TF_R(26) TF_R(6)
  x0 += k0; x1 += k1 + 3u;
  TF_R(17) TF_R(29) TF_R(16) TF_R(24)
  x0 += k1; x1 += k2 + 4u;
  TF_R(13) TF_R(15) TF_R(26) TF_R(6)
  x0 += k2; x1 += k0 + 5u;
#undef TF_R
  o0 = x0; o1 = x1;
}

__device__ __forceinline__ float bits_to_gumbel(unsigned bits) {
  unsigned fb = (bits >> 9) | 0x3f800000u;
  float u = __uint_as_float(fb) - 1.0f;
  u = u + 1.17549435e-38f;
  u = fmaxf(1.17549435e-38f, u);
  return -logf(-logf(u));
}

__device__ __forceinline__ float decode_temp(const void* temp_p) {
  float tf = *(const float*)temp_p;
  float a = fabsf(tf);
  if (a > 1e-6f && a < 1e6f) return tf;
  int ti = *(const int*)temp_p;
  if (ti != 0 && ti > -1000000 && ti < 1000000) return (float)ti;
  double td = *(const double*)temp_p;
  double ad = fabs(td);
  if (ad > 1e-6 && ad < 1e6) return (float)td;
  return 1.0f;
}

// MALL-coherent scalar access (bypasses L1/L2): no cache maintenance needed.
__device__ __forceinline__ void scld8(const float* p, float& a, float& b) {
  unsigned long long v = __hip_atomic_load((const unsigned long long*)p,
                                           __ATOMIC_RELAXED, __HIP_MEMORY_SCOPE_SYSTEM);
  union { unsigned long long u; float f[2]; } cv; cv.u = v;
  a = cv.f[0]; b = cv.f[1];
}
__device__ __forceinline__ void scst(float* p, float v) {
  __hip_atomic_store(p, v, __ATOMIC_RELAXED, __HIP_MEMORY_SCOPE_SYSTEM);
}

// split-phase grid barrier (monotonic counter). All cross-WG data is sc0sc1,
// so only store completion (drained by the s_barrier in __syncthreads) is
// needed before the arrival increment — no L2 invalidation, ever.
__device__ __forceinline__ void bar_arrive(unsigned* ctr, unsigned& barno) {
  __syncthreads();
  if (threadIdx.x == 0) {
    asm volatile("s_waitcnt vmcnt(0)" ::: "memory");
    __hip_atomic_fetch_add(ctr, 1u, __ATOMIC_RELAXED, __HIP_MEMORY_SCOPE_SYSTEM);
  }
  barno += 1;
}
__device__ __forceinline__ void bar_wait(unsigned* ctr, unsigned barno) {
  if (threadIdx.x == 0) {
    unsigned tgt = barno * NWG;
    while (__hip_atomic_load(ctr, __ATOMIC_RELAXED, __HIP_MEMORY_SCOPE_SYSTEM) < tgt)
      __builtin_amdgcn_s_sleep(1);
  }
  __syncthreads();
}

__global__ void k_init(unsigned* ctr) {
  if (threadIdx.x == 0 && blockIdx.x == 0) *ctr = 0u;
}
__global__ void k_diag(float* out, float v) {
  if (threadIdx.x == 0 && blockIdx.x == 0) out[0] = v;
}

// ===========================================================================
__global__ void __launch_bounds__(NT)
policy_persist(const void* temp_p,
               const float* __restrict__ h0_in, const float* __restrict__ c0_in,
               const float* __restrict__ Wih0,  const float* __restrict__ Whh0,
               const float* __restrict__ bih0,  const float* __restrict__ bhh0,
               const float* __restrict__ Wih1,  const float* __restrict__ Whh1,
               const float* __restrict__ bih1,  const float* __restrict__ bhh1,
               const float* __restrict__ emb,   const float* __restrict__ cW1,
               const float* __restrict__ cb1,   const float* __restrict__ cW2,
               const float* __restrict__ cb2,
               float* __restrict__ out, float* ws, unsigned* ctr) {
  __shared__ __align__(16) float shp0[H], shp1[H], hm[H];
  __shared__ float g0pre[16], g1bpre[16], g1loc[16];
  __shared__ float ewloc[12 * 16], b0loc[16], b1loc[16];
  __shared__ float gum[E * OPS];
  __shared__ float w1s[512 * 5];          // W1[i] slice, stride-5 padded
  __shared__ float w2s[512 * 13];         // W2[i] slice, stride-13 padded
  __shared__ float c0loc[4], c1loc[4];
  __shared__ float spart[4][4];
  __shared__ int s_act;

  const int tid = threadIdx.x;
  const int bid = blockIdx.x;
  const int j0  = bid * 4;                       // owned h-columns
  const int cb  = (bid & 7) * 16 + (bid >> 3);   // XCD-grouped HM col-block
  unsigned barno = 0;
  const float invt = 1.f / decode_temp(temp_p);

  float* HB = ws + WS_HB;
  float* HM = ws + WS_HM;

  // ---------------- setup (all WG-local; no grid sync needed) --------------
  for (int p = tid; p < E * OPS; p += NT) {
    unsigned y0, y1;
    threefry_42(0u, (unsigned)p, y0, y1);
    gum[p] = bits_to_gumbel(y0 ^ y1);
  }
  for (int j = tid; j < H; j += NT) {
    shp0[j] = h0_in[j];
    shp1[j] = h0_in[H + j];
  }
  if (tid < 192) {
    int a = tid / 16, ridx = tid % 16;
    int g = ridx >> 2, dj = ridx & 3;
    int row = g * H + j0 + dj;
    const float* er = emb + a * H;
    const float* wr = Wih0 + (size_t)row * H;
    float acc = 0.f;
    for (int k = 0; k < H; k += 4) {
      float4 e4 = *(const float4*)(er + k);
      float4 w4 = *(const float4*)(wr + k);
      acc += e4.x * w4.x + e4.y * w4.y + e4.z * w4.z + e4.w * w4.w;
    }
    ewloc[tid] = acc;
  }
  if (tid < 16) {
    int g = tid >> 2, dj = tid & 3;
    int row = g * H + j0 + dj;
    b0loc[tid] = bih0[row] + bhh0[row];
    b1loc[tid] = bih1[row] + bhh1[row];
  }
  if (tid < 4) {
    c0loc[tid] = c0_in[j0 + tid];
    c1loc[tid] = c0_in[H + j0 + tid];
  }
  __syncthreads();

  // G-pre for step 0 (from initial h) + W1[0] prefetch
  {
    // GPRE: g0pre = Whh0@h + B0 (own 16 rows); g1bpre = Whh1@h (own 16 rows)
    int rowidx = tid >> 3, lane = tid & 7;
    int cell = rowidx >> 4, ridx = rowidx & 15;
    int g = ridx >> 2, dj = ridx & 3;
    int row = g * H + j0 + dj;
    const float* wr = (cell ? Whh1 : Whh0) + (size_t)row * H + lane * 64;
    const float* hv = (cell ? shp1 : shp0) + lane * 64;
    float acc = 0.f;
#pragma unroll
    for (int k = 0; k < 64; k += 4) {
      float4 w4 = *(const float4*)(wr + k);
      acc += w4.x * hv[k] + w4.y * hv[k + 1] + w4.z * hv[k + 2] + w4.w * hv[k + 3];
    }
    acc += __shfl_xor(acc, 1);
    acc += __shfl_xor(acc, 2);
    acc += __shfl_xor(acc, 4);
    if (lane == 0) {
      if (cell == 0) g0pre[ridx] = acc + b0loc[ridx];
      else           g1bpre[ridx] = acc;
    }
    // W1[0] slice prefetch (reg-staged -> LDS, stride-5)
    const float* wb = cW1 + (size_t)cb * 4;
    float4 r0 = *(const float4*)(wb + (size_t)tid * H);
    float4 r1 = *(const float4*)(wb + (size_t)(tid + 256) * H);
    int k0 = tid * 5, k1 = (tid + 256) * 5;
    w1s[k0] = r0.x; w1s[k0 + 1] = r0.y; w1s[k0 + 2] = r0.z; w1s[k0 + 3] = r0.w;
    w1s[k1] = r1.x; w1s[k1 + 1] = r1.y; w1s[k1 + 2] = r1.z; w1s[k1 + 3] = r1.w;
  }
  __syncthreads();

#pragma unroll 1
  for (int i = 0; i < E; ++i) {
    // ---- sampling of step i-1 (HM synced at prev b3; w2s = W2[i-1]) ------
    if (i > 0) {
      int t2 = tid * 2;
      scld8(&HM[t2], hm[t2], hm[t2 + 1]);
      __syncthreads();
      if (tid < 64) {
        float lg[OPS];
#pragma unroll
        for (int o = 0; o < OPS; ++o) lg[o] = 0.f;
#pragma unroll
        for (int jj = 0; jj < 8; ++jj) {
          int j = jj * 64 + tid;
          float hmv = hm[j];
          const float* w2r = &w2s[j * 13];
#pragma unroll
          for (int o = 0; o < OPS; ++o) lg[o] += hmv * w2r[o];
        }
#pragma unroll
        for (int s = 1; s < 64; s <<= 1) {
#pragma unroll
          for (int o = 0; o < OPS; ++o) lg[o] += __shfl_xor(lg[o], s);
        }
#pragma unroll
        for (int o = 0; o < OPS; ++o) lg[o] = (lg[o] + cb2[(i - 1) * OPS + o]) * invt;
        float mx = lg[0];
#pragma unroll
        for (int o = 1; o < OPS; ++o) mx = fmaxf(mx, lg[o]);
        float se = 0.f;
#pragma unroll
        for (int o = 0; o < OPS; ++o) se += expf(lg[o] - mx);
        float logZ = mx + logf(se);
        float best = -1e30f; int act = 0;
#pragma unroll
        for (int o = 0; o < OPS; ++o) {
          float v = lg[o] + gum[(i - 1) * OPS + o];
          if (v > best) { best = v; act = o; }
        }
        if (tid == 0) {
          s_act = act;
          if (bid == 0) {
            float lp = lg[act] - logZ;
            float ent = 0.f;
            for (int o = 0; o < OPS; ++o) {
              float l2 = lg[o] - logZ;
              ent -= expf(l2) * l2;
            }
            out[i - 1]         = (float)act;
            out[E + i - 1]     = lp;
            out[2 * E + i - 1] = ent;
          }
        }
      }
    }

    // ---- PW0 (own 4 cols): G0 = g0pre (+EW[a]); -> h0n sc store ----------
    // s_act written by tid0 and read by tid0..3: same wave, no barrier needed
    if (tid < 4) {
      int a = (i > 0) ? s_act : -1;
      float gi = g0pre[tid];
      float gf = g0pre[4 + tid];
      float gg = g0pre[8 + tid];
      float go = g0pre[12 + tid];
      if (a >= 0) {
        gi += ewloc[a * 16 + tid];
        gf += ewloc[a * 16 + 4 + tid];
        gg += ewloc[a * 16 + 8 + tid];
        go += ewloc[a * 16 + 12 + tid];
      }
      float cn = sigf(gf) * c0loc[tid] + sigf(gi) * tanhf(gg);
      c0loc[tid] = cn;
      scst(&HB[j0 + tid], sigf(go) * tanhf(cn));
    }
    bar_arrive(ctr, barno);                        // b1 arrive
    bar_wait(ctr, barno);                          // b1 wait

    // ---- G1 = Wih1@h0n + G1Bpre + B1; PW1 -> h1n sc store ----------------
    {
      int t2 = tid * 2;
      float a0, a1;
      scld8(&HB[t2], a0, a1);
      shp0[t2] = a0; shp0[t2 + 1] = a1;
    }
    __syncthreads();
    {
      int ridx = tid >> 4, lane = tid & 15;
      int g = ridx >> 2, dj = ridx & 3;
      int row = g * H + j0 + dj;
      const float* wr = Wih1 + (size_t)row * H + lane * 32;
      const float* hv = shp0 + lane * 32;
      float acc = 0.f;
#pragma unroll
      for (int k = 0; k < 32; k += 4) {
        float4 w4 = *(const float4*)(wr + k);
        acc += w4.x * hv[k] + w4.y * hv[k + 1] + w4.z * hv[k + 2] + w4.w * hv[k + 3];
      }
      acc += __shfl_xor(acc, 1);
      acc += __shfl_xor(acc, 2);
      acc += __shfl_xor(acc, 4);
      acc += __shfl_xor(acc, 8);
      if (lane == 0) g1loc[ridx] = acc + g1bpre[ridx] + b1loc[ridx];
    }
    __syncthreads();
    if (tid < 4) {
      float gi = g1loc[tid];
      float gf = g1loc[4 + tid];
      float gg = g1loc[8 + tid];
      float go = g1loc[12 + tid];
      float cn = sigf(gf) * c1loc[tid] + sigf(gi) * tanhf(gg);
      c1loc[tid] = cn;
      scst(&HB[H + j0 + tid], sigf(go) * tanhf(cn));
    }
    bar_arrive(ctr, barno);                        // b2 arrive
    // ---- b2 shadow: prefetch W2[i] -> w2s (consumed at step i+1 top) -----
    {
      const float* wsrc = cW2 + (size_t)i * H * OPS;
#pragma unroll
      for (int r = 0; r < 6; ++r) {
        int q = tid + 256 * r;                     // q < 1536
        float4 v = *(const float4*)(wsrc + 4 * q);
        int f = 4 * q;
        w2s[(f / 12) * 13 + (f % 12)]             = v.x;
        w2s[((f + 1) / 12) * 13 + ((f + 1) % 12)] = v.y;
        w2s[((f + 2) / 12) * 13 + ((f + 2) % 12)] = v.z;
        w2s[((f + 3) / 12) * 13 + ((f + 3) % 12)] = v.w;
      }
    }
    bar_wait(ctr, barno);                          // b2 wait

    // ---- phase C: HM cols [cb*4, cb*4+4) from LDS W1 ---------------------
    {
      int t2 = tid * 2;
      float a0, a1;
      scld8(&HB[H + t2], a0, a1);
      shp1[t2] = a0; shp1[t2 + 1] = a1;
    }
    __syncthreads();
    {
      int wv = tid >> 6, ln = tid & 63;
      int jl = ln & 3, ks = ln >> 2;
      int kbase = wv * 128 + ks * 8;
      float acc = 0.f;
#pragma unroll
      for (int t = 0; t < 8; ++t) {
        int k = kbase + t;
        acc += shp1[k] * w1s[k * 5 + jl];
      }
      acc += __shfl_xor(acc, 4);
      acc += __shfl_xor(acc, 8);
      acc += __shfl_xor(acc, 16);
      acc += __shfl_xor(acc, 32);
      if (ln < 4) spart[wv][ln] = acc;
    }
    __syncthreads();
    if (tid < 4) {
      float s = spart[0][tid] + spart[1][tid] + spart[2][tid] + spart[3][tid];
      s += cb1[(size_t)i * H + cb * 4 + tid];
      scst(&HM[cb * 4 + tid], fmaxf(s, 0.f));
    }
    bar_arrive(ctr, barno);                        // b3 arrive
    // ---- b3 shadow: W1[i+1] prefetch + next-step G-pre matvecs -----------
    if (i + 1 < E) {
      const float* wb = cW1 + (size_t)(i + 1) * H * H + (size_t)cb * 4;
      float4 r0 = *(const float4*)(wb + (size_t)tid * H);
      float4 r1 = *(const float4*)(wb + (size_t)(tid + 256) * H);
      {
        int rowidx = tid >> 3, lane = tid & 7;
        int cell = rowidx >> 4, ridx = rowidx & 15;
        int g = ridx >> 2, dj = ridx & 3;
        int row = g * H + j0 + dj;
        const float* wr = (cell ? Whh1 : Whh0) + (size_t)row * H + lane * 64;
        const float* hv = (cell ? shp1 : shp0) + lane * 64;
        float acc = 0.f;
#pragma unroll
        for (int k = 0; k < 64; k += 4) {
          float4 w4 = *(const float4*)(wr + k);
          acc += w4.x * hv[k] + w4.y * hv[k + 1] + w4.z * hv[k + 2] + w4.w * hv[k + 3];
        }
        acc += __shfl_xor(acc, 1);
        acc += __shfl_xor(acc, 2);
        acc += __shfl_xor(acc, 4);
        if (lane == 0) {
          if (cell == 0) g0pre[ridx] = acc + b0loc[ridx];
          else           g1bpre[ridx] = acc;
        }
      }
      int k0 = tid * 5, k1 = (tid + 256) * 5;
      w1s[k0] = r0.x; w1s[k0 + 1] = r0.y; w1s[k0 + 2] = r0.z; w1s[k0 + 3] = r0.w;
      w1s[k1] = r1.x; w1s[k1 + 1] = r1.y; w1s[k1 + 2] = r1.z; w1s[k1 + 3] = r1.w;
    }
    bar_wait(ctr, barno);                          // b3 wait
  }

  // ---- final sampling (step E-1); w2s = W2[E-1] ---------------------------
  {
    int t2 = tid * 2;
    scld8(&HM[t2], hm[t2], hm[t2 + 1]);
  }
  __syncthreads();
  if (bid == 0 && tid < 64) {
    float lg[OPS];
#pragma unroll
    for (int o = 0; o < OPS; ++o) lg[o] = 0.f;
#pragma unroll
    for (int jj = 0; jj < 8; ++jj) {
      int j = jj * 64 + tid;
      float hmv = hm[j];
      const float* w2r = &w2s[j * 13];
#pragma unroll
      for (int o = 0; o < OPS; ++o) lg[o] += hmv * w2r[o];
    }
#pragma unroll
    for (int s = 1; s < 64; s <<= 1) {
#pragma unroll
      for (int o = 0; o < OPS; ++o) lg[o] += __shfl_xor(lg[o], s);
    }
#pragma unroll
    for (int o = 0; o < OPS; ++o) lg[o] = (lg[o] + cb2[(E - 1) * OPS + o]) * invt;
    float mx = lg[0];
#pragma unroll
    for (int o = 1; o < OPS; ++o) mx = fmaxf(mx, lg[o]);
    float se = 0.f;
#pragma unroll
    for (int o = 0; o < OPS; ++o) se += expf(lg[o] - mx);
    float logZ = mx + logf(se);
    float best = -1e30f; int act = 0;
#pragma unroll
    for (int o = 0; o < OPS; ++o) {
      float v = lg[o] + gum[(E - 1) * OPS + o];
      if (v > best) { best = v; act = o; }
    }
    if (tid == 0) {
      float lp = lg[act] - logZ;
      float ent = 0.f;
      for (int o = 0; o < OPS; ++o) {
        float l2 = lg[o] - logZ;
        ent -= expf(l2) * l2;
      }
      out[E - 1]     = (float)act;
      out[2 * E - 1] = lp;
      out[3 * E - 1] = ent;
    }
  }
}

// ===========================================================================
extern "C" void kernel_launch(void* const* d_in, const int* in_sizes, int n_in,
                              void* d_out, int out_size, void* d_ws, size_t ws_size,
                              hipStream_t stream) {
  (void)out_size; (void)ws_size;
  float* out = (float*)d_out;
  float* ws  = (float*)d_ws;
  unsigned* ctr = (unsigned*)d_ws;

  (void)hipGetLastError();

  static const long long expect[16] = {
      1, 1024, 1024, 1048576, 1048576, 2048, 2048,
      1048576, 1048576, 2048, 2048, 6144,
      29360128, 57344, 688128, 1344 };
  int bad = -1;
  if (n_in != 16) bad = 99;
  else {
    for (int i = 0; i < 16; ++i)
      if ((long long)in_sizes[i] != expect[i]) { bad = i; break; }
  }

  k_init<<<1, 64, 0, stream>>>(ctr);
  if (bad >= 0) {
    k_diag<<<1, 64, 0, stream>>>(out, 80000.0f + (float)bad);
    return;
  }

  policy_persist<<<NWG, NT, 0, stream>>>(
      d_in[0],
      (const float*)d_in[1],  (const float*)d_in[2],
      (const float*)d_in[3],  (const float*)d_in[4],
      (const float*)d_in[5],  (const float*)d_in[6],
      (const float*)d_in[7],  (const float*)d_in[8],
      (const float*)d_in[9],  (const float*)d_in[10],
      (const float*)d_in[11], (const float*)d_in[12],
      (const float*)d_in[13], (const float*)d_in[14],
      (const float*)d_in[15],
      out, ws, ctr);

  hipError_t e = hipGetLastError();
  if (e != hipSuccess) {
    k_diag<<<1, 64, 0, stream>>>(out, 90000.0f + (float)(int)e);
  }
}

// Round 9
// 1073.802 us; speedup vs baseline: 7.4162x; 1.4063x over previous
//
#include <hip/hip_runtime.h>
#include <math.h>

#define H    512
#define OPS  12
#define E    112
#define NWG  128
#define NT   256

typedef unsigned long long u64;

// ws: first 16 floats reserved; then 3072 u64 tagged words:
//   HB0[2][512] (h0n), HB1[2][512] (h1n), HMB[2][512] (controller hidden)
#define TW_BASE  16
#define TW_HB0   0
#define TW_HB1   1024
#define TW_HMB   2048
#define TW_TOTAL 3072

__device__ __forceinline__ float sigf(float x) { return 1.f / (1.f + expf(-x)); }

// JAX threefry2x32, key = PRNGKey(42) = (0,42), 20 rounds
__device__ __forceinline__ void threefry_42(unsigned x0, unsigned x1,
                                            unsigned& o0, unsigned& o1) {
  const unsigned k0 = 0u, k1 = 42u;
  const unsigned k2 = k0 ^ k1 ^ 0x1BD11BDAu;
  x0 += k0; x1 += k1;
#define TF_R(rot) { x0 += x1; x1 = (x1 << rot) | (x1 >> (32 - rot)); x1 ^= x0; }
  TF_R(13) TF_R(15) TF_R(26) TF_R(6)
  x0 += k1; x1 += k2 + 1u;
  TF_R(17) TF_R(29) TF_R(16) TF_R(24)
  x0 += k2; x1 += k0 + 2u;
  TF_R(13) TF_R(15) TF_R(26) TF_R(6)
  x0 += k0; x1 += k1 + 3u;
  TF_R(17) TF_R(29) TF_R(16) TF_R(24)
  x0 += k1; x1 += k2 + 4u;
  TF_R(13) TF_R(15) TF_R(26) TF_R(6)
  x0 += k2; x1 += k0 + 5u;
#undef TF_R
  o0 = x0; o1 = x1;
}

__device__ __forceinline__ float bits_to_gumbel(unsigned bits) {
  unsigned fb = (bits >> 9) | 0x3f800000u;
  float u = __uint_as_float(fb) - 1.0f;
  u = u + 1.17549435e-38f;
  u = fmaxf(1.17549435e-38f, u);
  return -logf(-logf(u));
}

__device__ __forceinline__ float decode_temp(const void* temp_p) {
  float tf = *(const float*)temp_p;
  float a = fabsf(tf);
  if (a > 1e-6f && a < 1e6f) return tf;
  int ti = *(const int*)temp_p;
  if (ti != 0 && ti > -1000000 && ti < 1000000) return (float)ti;
  double td = *(const double*)temp_p;
  double ad = fabs(td);
  if (ad > 1e-6 && ad < 1e6) return (float)td;
  return 1.0f;
}

// MALL-coherent tagged-word transport. Single 64-bit atomic word carries
// (tag << 32 | float bits): readiness and value in one transaction, so no
// fences, no barriers, no cache maintenance are needed anywhere.
__device__ __forceinline__ void tag_store(u64* p, unsigned tag, float f) {
  u64 v = ((u64)tag << 32) | (u64)__float_as_uint(f);
  __hip_atomic_store(p, v, __ATOMIC_RELAXED, __HIP_MEMORY_SCOPE_SYSTEM);
}
__device__ __forceinline__ float tag_poll(const u64* p, unsigned tag) {
  u64 v = __hip_atomic_load(p, __ATOMIC_RELAXED, __HIP_MEMORY_SCOPE_SYSTEM);
  while ((unsigned)(v >> 32) != tag) {
    __builtin_amdgcn_s_sleep(1);
    v = __hip_atomic_load(p, __ATOMIC_RELAXED, __HIP_MEMORY_SCOPE_SYSTEM);
  }
  return __uint_as_float((unsigned)v);
}

__global__ void k_init(u64* tw) {
  int t = blockIdx.x * blockDim.x + threadIdx.x;
  if (t < TW_TOTAL) tw[t] = 0ull;
}
__global__ void k_diag(float* out, float v) {
  if (threadIdx.x == 0 && blockIdx.x == 0) out[0] = v;
}

// ===========================================================================
__global__ void __launch_bounds__(NT)
policy_persist(const void* temp_p,
               const float* __restrict__ h0_in, const float* __restrict__ c0_in,
               const float* __restrict__ Wih0,  const float* __restrict__ Whh0,
               const float* __restrict__ bih0,  const float* __restrict__ bhh0,
               const float* __restrict__ Wih1,  const float* __restrict__ Whh1,
               const float* __restrict__ bih1,  const float* __restrict__ bhh1,
               const float* __restrict__ emb,   const float* __restrict__ cW1,
               const float* __restrict__ cb1,   const float* __restrict__ cW2,
               const float* __restrict__ cb2,
               float* __restrict__ out, float* ws) {
  __shared__ __align__(16) float shp0[H], shp1[H], hm[H];
  __shared__ float g0pre[16], g1bpre[16], g1loc[16];
  __shared__ float ewloc[12 * 16], b0loc[16], b1loc[16];
  __shared__ float gum[E * OPS];
  __shared__ float w1s[512 * 5];          // W1[i] slice, stride-5 padded
  __shared__ float w2s[512 * 13];         // W2[i] slice, stride-13 padded
  __shared__ float c0loc[4], c1loc[4];
  __shared__ float spart[4][4];
  __shared__ int s_act;

  const int tid = threadIdx.x;
  const int bid = blockIdx.x;
  const int j0  = bid * 4;                       // owned h-columns
  const int cb  = (bid & 7) * 16 + (bid >> 3);   // XCD-grouped HM col-block
  const float invt = 1.f / decode_temp(temp_p);

  u64* HB0 = (u64*)(ws + TW_BASE) + TW_HB0;
  u64* HB1 = (u64*)(ws + TW_BASE) + TW_HB1;
  u64* HMB = (u64*)(ws + TW_BASE) + TW_HMB;

  // ---------------- setup (all WG-local; no cross-WG sync needed) ----------
  for (int p = tid; p < E * OPS; p += NT) {
    unsigned y0, y1;
    threefry_42(0u, (unsigned)p, y0, y1);
    gum[p] = bits_to_gumbel(y0 ^ y1);
  }
  for (int j = tid; j < H; j += NT) {
    shp0[j] = h0_in[j];
    shp1[j] = h0_in[H + j];
  }
  if (tid < 192) {
    int a = tid / 16, ridx = tid % 16;
    int g = ridx >> 2, dj = ridx & 3;
    int row = g * H + j0 + dj;
    const float* er = emb + a * H;
    const float* wr = Wih0 + (size_t)row * H;
    float acc = 0.f;
    for (int k = 0; k < H; k += 4) {
      float4 e4 = *(const float4*)(er + k);
      float4 w4 = *(const float4*)(wr + k);
      acc += e4.x * w4.x + e4.y * w4.y + e4.z * w4.z + e4.w * w4.w;
    }
    ewloc[tid] = acc;
  }
  if (tid < 16) {
    int g = tid >> 2, dj = tid & 3;
    int row = g * H + j0 + dj;
    b0loc[tid] = bih0[row] + bhh0[row];
    b1loc[tid] = bih1[row] + bhh1[row];
  }
  if (tid < 4) {
    c0loc[tid] = c0_in[j0 + tid];
    c1loc[tid] = c0_in[H + j0 + tid];
  }
  __syncthreads();

  // G-pre for step 0 + W1[0] prefetch (identical math to round 8)
  {
    int rowidx = tid >> 3, lane = tid & 7;
    int cell = rowidx >> 4, ridx = rowidx & 15;
    int g = ridx >> 2, dj = ridx & 3;
    int row = g * H + j0 + dj;
    const float* wr = (cell ? Whh1 : Whh0) + (size_t)row * H + lane * 64;
    const float* hv = (cell ? shp1 : shp0) + lane * 64;
    float acc = 0.f;
#pragma unroll
    for (int k = 0; k < 64; k += 4) {
      float4 w4 = *(const float4*)(wr + k);
      acc += w4.x * hv[k] + w4.y * hv[k + 1] + w4.z * hv[k + 2] + w4.w * hv[k + 3];
    }
    acc += __shfl_xor(acc, 1);
    acc += __shfl_xor(acc, 2);
    acc += __shfl_xor(acc, 4);
    if (lane == 0) {
      if (cell == 0) g0pre[ridx] = acc + b0loc[ridx];
      else           g1bpre[ridx] = acc;
    }
    const float* wb = cW1 + (size_t)cb * 4;
    float4 r0 = *(const float4*)(wb + (size_t)tid * H);
    float4 r1 = *(const float4*)(wb + (size_t)(tid + 256) * H);
    int k0 = tid * 5, k1 = (tid + 256) * 5;
    w1s[k0] = r0.x; w1s[k0 + 1] = r0.y; w1s[k0 + 2] = r0.z; w1s[k0 + 3] = r0.w;
    w1s[k1] = r1.x; w1s[k1 + 1] = r1.y; w1s[k1 + 2] = r1.z; w1s[k1 + 3] = r1.w;
  }
  __syncthreads();

#pragma unroll 1
  for (int i = 0; i < E; ++i) {
    const int p = i & 1;
    const unsigned tg = (unsigned)(i + 1);

    // ---- 1: sampling of step i-1 (poll HM tag i; w2s = W2[i-1]) ----------
    if (i > 0) {
      const int q = (i - 1) & 1;
      const unsigned tgp = (unsigned)i;
      int t2 = tid * 2;
      hm[t2]     = tag_poll(&HMB[q * 512 + t2],     tgp);
      hm[t2 + 1] = tag_poll(&HMB[q * 512 + t2 + 1], tgp);
      __syncthreads();
      if (tid < 64) {
        float lg[OPS];
#pragma unroll
        for (int o = 0; o < OPS; ++o) lg[o] = 0.f;
#pragma unroll
        for (int jj = 0; jj < 8; ++jj) {
          int j = jj * 64 + tid;
          float hmv = hm[j];
          const float* w2r = &w2s[j * 13];
#pragma unroll
          for (int o = 0; o < OPS; ++o) lg[o] += hmv * w2r[o];
        }
#pragma unroll
        for (int s = 1; s < 64; s <<= 1) {
#pragma unroll
          for (int o = 0; o < OPS; ++o) lg[o] += __shfl_xor(lg[o], s);
        }
#pragma unroll
        for (int o = 0; o < OPS; ++o) lg[o] = (lg[o] + cb2[(i - 1) * OPS + o]) * invt;
        float mx = lg[0];
#pragma unroll
        for (int o = 1; o < OPS; ++o) mx = fmaxf(mx, lg[o]);
        float se = 0.f;
#pragma unroll
        for (int o = 0; o < OPS; ++o) se += expf(lg[o] - mx);
        float logZ = mx + logf(se);
        float best = -1e30f; int act = 0;
#pragma unroll
        for (int o = 0; o < OPS; ++o) {
          float v = lg[o] + gum[(i - 1) * OPS + o];
          if (v > best) { best = v; act = o; }
        }
        if (tid == 0) {
          s_act = act;
          if (bid == 0) {
            float lp = lg[act] - logZ;
            float ent = 0.f;
            for (int o = 0; o < OPS; ++o) {
              float l2 = lg[o] - logZ;
              ent -= expf(l2) * l2;
            }
            out[i - 1]         = (float)act;
            out[E + i - 1]     = lp;
            out[2 * E + i - 1] = ent;
          }
        }
      }
    }

    // ---- 2: PW0 (own 4 cols) -> tagged h0n store --------------------------
    // s_act written by tid0, read by tid0..3: same wave, no barrier needed
    if (tid < 4) {
      int a = (i > 0) ? s_act : -1;
      float gi = g0pre[tid];
      float gf = g0pre[4 + tid];
      float gg = g0pre[8 + tid];
      float go = g0pre[12 + tid];
      if (a >= 0) {
        gi += ewloc[a * 16 + tid];
        gf += ewloc[a * 16 + 4 + tid];
        gg += ewloc[a * 16 + 8 + tid];
        go += ewloc[a * 16 + 12 + tid];
      }
      float cn = sigf(gf) * c0loc[tid] + sigf(gi) * tanhf(gg);
      c0loc[tid] = cn;
      tag_store(&HB0[p * 512 + j0 + tid], tg, sigf(go) * tanhf(cn));
    }

    // ---- 3: poll full h0n -------------------------------------------------
    {
      int t2 = tid * 2;
      shp0[t2]     = tag_poll(&HB0[p * 512 + t2],     tg);
      shp0[t2 + 1] = tag_poll(&HB0[p * 512 + t2 + 1], tg);
    }
    __syncthreads();

    // ---- 4: G1 = Wih1@h0n + G1Bpre + B1 (own 16 rows) ---------------------
    {
      int ridx = tid >> 4, lane = tid & 15;
      int g = ridx >> 2, dj = ridx & 3;
      int row = g * H + j0 + dj;
      const float* wr = Wih1 + (size_t)row * H + lane * 32;
      const float* hv = shp0 + lane * 32;
      float acc = 0.f;
#pragma unroll
      for (int k = 0; k < 32; k += 4) {
        float4 w4 = *(const float4*)(wr + k);
        acc += w4.x * hv[k] + w4.y * hv[k + 1] + w4.z * hv[k + 2] + w4.w * hv[k + 3];
      }
      acc += __shfl_xor(acc, 1);
      acc += __shfl_xor(acc, 2);
      acc += __shfl_xor(acc, 4);
      acc += __shfl_xor(acc, 8);
      if (lane == 0) g1loc[ridx] = acc + g1bpre[ridx] + b1loc[ridx];
    }
    __syncthreads();

    // ---- 5: PW1 (own 4 cols) -> tagged h1n store --------------------------
    if (tid < 4) {
      float gi = g1loc[tid];
      float gf = g1loc[4 + tid];
      float gg = g1loc[8 + tid];
      float go = g1loc[12 + tid];
      float cn = sigf(gf) * c1loc[tid] + sigf(gi) * tanhf(gg);
      c1loc[tid] = cn;
      tag_store(&HB1[p * 512 + j0 + tid], tg, sigf(go) * tanhf(cn));
    }

    // ---- 6: poll full h1n -------------------------------------------------
    {
      int t2 = tid * 2;
      shp1[t2]     = tag_poll(&HB1[p * 512 + t2],     tg);
      shp1[t2 + 1] = tag_poll(&HB1[p * 512 + t2 + 1], tg);
    }
    __syncthreads();

    // ---- 7: phase C -> tagged HM store ------------------------------------
    {
      int wv = tid >> 6, ln = tid & 63;
      int jl = ln & 3, ks = ln >> 2;
      int kbase = wv * 128 + ks * 8;
      float acc = 0.f;
#pragma unroll
      for (int t = 0; t < 8; ++t) {
        int k = kbase + t;
        acc += shp1[k] * w1s[k * 5 + jl];
      }
      acc += __shfl_xor(acc, 4);
      acc += __shfl_xor(acc, 8);
      acc += __shfl_xor(acc, 16);
      acc += __shfl_xor(acc, 32);
      if (ln < 4) spart[wv][ln] = acc;
    }
    __syncthreads();
    if (tid < 4) {
      float s = spart[0][tid] + spart[1][tid] + spart[2][tid] + spart[3][tid];
      s += cb1[(size_t)i * H + cb * 4 + tid];
      tag_store(&HMB[p * 512 + cb * 4 + tid], tg, fmaxf(s, 0.f));
    }

    // ---- 8: shadow work: W2[i] -> w2s; W1[i+1] -> w1s; G-pre[i+1] ---------
    {
      const float* wsrc = cW2 + (size_t)i * H * OPS;
#pragma unroll
      for (int r = 0; r < 6; ++r) {
        int q = tid + 256 * r;                     // q < 1536
        float4 v = *(const float4*)(wsrc + 4 * q);
        int f = 4 * q;
        w2s[(f / 12) * 13 + (f % 12)]             = v.x;
        w2s[((f + 1) / 12) * 13 + ((f + 1) % 12)] = v.y;
        w2s[((f + 2) / 12) * 13 + ((f + 2) % 12)] = v.z;
        w2s[((f + 3) / 12) * 13 + ((f + 3) % 12)] = v.w;
      }
    }
    if (i + 1 < E) {
      const float* wb = cW1 + (size_t)(i + 1) * H * H + (size_t)cb * 4;
      float4 r0 = *(const float4*)(wb + (size_t)tid * H);
      float4 r1 = *(const float4*)(wb + (size_t)(tid + 256) * H);
      {
        int rowidx = tid >> 3, lane = tid & 7;
        int cell = rowidx >> 4, ridx = rowidx & 15;
        int g = ridx >> 2, dj = ridx & 3;
        int row = g * H + j0 + dj;
        const float* wr = (cell ? Whh1 : Whh0) + (size_t)row * H + lane * 64;
        const float* hv = (cell ? shp1 : shp0) + lane * 64;
        float acc = 0.f;
#pragma unroll
        for (int k = 0; k < 64; k += 4) {
          float4 w4 = *(const float4*)(wr + k);
          acc += w4.x * hv[k] + w4.y * hv[k + 1] + w4.z * hv[k + 2] + w4.w * hv[k + 3];
        }
        acc += __shfl_xor(acc, 1);
        acc += __shfl_xor(acc, 2);
        acc += __shfl_xor(acc, 4);
        if (lane == 0) {
          if (cell == 0) g0pre[ridx] = acc + b0loc[ridx];
          else           g1bpre[ridx] = acc;
        }
      }
      int k0 = tid * 5, k1 = (tid + 256) * 5;
      w1s[k0] = r0.x; w1s[k0 + 1] = r0.y; w1s[k0 + 2] = r0.z; w1s[k0 + 3] = r0.w;
      w1s[k1] = r1.x; w1s[k1 + 1] = r1.y; w1s[k1 + 2] = r1.z; w1s[k1 + 3] = r1.w;
    }
    __syncthreads();
  }

  // ---- final sampling (step E-1); w2s = W2[E-1] ---------------------------
  if (bid == 0) {
    const int q = (E - 1) & 1;
    int t2 = tid * 2;
    hm[t2]     = tag_poll(&HMB[q * 512 + t2],     (unsigned)E);
    hm[t2 + 1] = tag_poll(&HMB[q * 512 + t2 + 1], (unsigned)E);
    __syncthreads();
    if (tid < 64) {
      float lg[OPS];
#pragma unroll
      for (int o = 0; o < OPS; ++o) lg[o] = 0.f;
#pragma unroll
      for (int jj = 0; jj < 8; ++jj) {
        int j = jj * 64 + tid;
        float hmv = hm[j];
        const float* w2r = &w2s[j * 13];
#pragma unroll
        for (int o = 0; o < OPS; ++o) lg[o] += hmv * w2r[o];
      }
#pragma unroll
      for (int s = 1; s < 64; s <<= 1) {
#pragma unroll
        for (int o = 0; o < OPS; ++o) lg[o] += __shfl_xor(lg[o], s);
      }
#pragma unroll
      for (int o = 0; o < OPS; ++o) lg[o] = (lg[o] + cb2[(E - 1) * OPS + o]) * invt;
      float mx = lg[0];
#pragma unroll
      for (int o = 1; o < OPS; ++o) mx = fmaxf(mx, lg[o]);
      float se = 0.f;
#pragma unroll
      for (int o = 0; o < OPS; ++o) se += expf(lg[o] - mx);
      float logZ = mx + logf(se);
      float best = -1e30f; int act = 0;
#pragma unroll
      for (int o = 0; o < OPS; ++o) {
        float v = lg[o] + gum[(E - 1) * OPS + o];
        if (v > best) { best = v; act = o; }
      }
      if (tid == 0) {
        float lp = lg[act] - logZ;
        float ent = 0.f;
        for (int o = 0; o < OPS; ++o) {
          float l2 = lg[o] - logZ;
          ent -= expf(l2) * l2;
        }
        out[E - 1]     = (float)act;
        out[2 * E - 1] = lp;
        out[3 * E - 1] = ent;
      }
    }
  }
}

// ===========================================================================
extern "C" void kernel_launch(void* const* d_in, const int* in_sizes, int n_in,
                              void* d_out, int out_size, void* d_ws, size_t ws_size,
                              hipStream_t stream) {
  (void)out_size; (void)ws_size;
  float* out = (float*)d_out;
  float* ws  = (float*)d_ws;

  (void)hipGetLastError();

  static const long long expect[16] = {
      1, 1024, 1024, 1048576, 1048576, 2048, 2048,
      1048576, 1048576, 2048, 2048, 6144,
      29360128, 57344, 688128, 1344 };
  int bad = -1;
  if (n_in != 16) bad = 99;
  else {
    for (int i = 0; i < 16; ++i)
      if ((long long)in_sizes[i] != expect[i]) { bad = i; break; }
  }

  k_init<<<12, 256, 0, stream>>>((u64*)(ws + TW_BASE));
  if (bad >= 0) {
    k_diag<<<1, 64, 0, stream>>>(out, 80000.0f + (float)bad);
    return;
  }

  policy_persist<<<NWG, NT, 0, stream>>>(
      d_in[0],
      (const float*)d_in[1],  (const float*)d_in[2],
      (const float*)d_in[3],  (const float*)d_in[4],
      (const float*)d_in[5],  (const float*)d_in[6],
      (const float*)d_in[7],  (const float*)d_in[8],
      (const float*)d_in[9],  (const float*)d_in[10],
      (const float*)d_in[11], (const float*)d_in[12],
      (const float*)d_in[13], (const float*)d_in[14],
      (const float*)d_in[15],
      out, ws);

  hipError_t e = hipGetLastError();
  if (e != hipSuccess) {
    k_diag<<<1, 64, 0, stream>>>(out, 90000.0f + (float)(int)e);
  }
}